// Round 14
// baseline (146.358 us; speedup 1.0000x reference)
//
#include <hip/hip_runtime.h>
#include <hip/hip_fp16.h>
#include <cstdint>
#include <cstddef>

constexpr int R  = 512;
constexpr int C  = 16;
constexpr int HW = R * R;

constexpr int NB9   = 512;    // coarse bins: 3 bits/axis (64px cells)
constexpr int NPART = 8;      // XCD partitions for coarse counters
constexpr int NCNT  = NB9 * NPART;
constexpr int CHUNK = 4096;   // pts/block in hist/scatter
constexpr int KMX   = 9;      // fused sampler: sortable recs per thread
constexpr int KCAP  = KMX * 512;   // 4608 sorted-capacity per coarse bin

typedef float v4f __attribute__((ext_vector_type(4)));
typedef int   v4i __attribute__((ext_vector_type(4)));

// ---- unified, bit-exact coordinate helpers ----------
__device__ __forceinline__ float tcoord(float g) {
    return __fmul_rn(__fadd_rn(g, 1.0f), 255.5f);   // bit-exact == ((g+1)*0.5f)*511
}
__device__ __forceinline__ int cell512(float g) {
    const int i = (int)tcoord(g);
    return min(max(i, 0), R - 1);
}
__device__ __forceinline__ uint32_t mortonN(int a, int b, int c, int nb) {
    uint32_t k = 0;
#pragma unroll
    for (int i = 0; i < 5; ++i) {
        if (i < nb) {
            k |= ((uint32_t)((a >> i) & 1)) << (3 * i + 2);
            k |= ((uint32_t)((b >> i) & 1)) << (3 * i + 1);
            k |= ((uint32_t)((c >> i) & 1)) << (3 * i + 0);
        }
    }
    return k;
}
__device__ __forceinline__ uint32_t key9(float a, float b, float c) {
    return mortonN(cell512(a) >> 6, cell512(b) >> 6, cell512(c) >> 6, 3);
}

// ---- forced-MLP gather primitives (inline asm, SADDR + 32-bit voffset) ----
__device__ __forceinline__ v4i gload16(const void* base, uint32_t voff) {
    v4i r;
    asm volatile("global_load_dwordx4 %0, %1, %2"
                 : "=&v"(r) : "v"(voff), "s"(base));
    return r;
}
#define VMWAIT(N) do { \
    asm volatile("s_waitcnt vmcnt(" #N ")" ::: "memory"); \
    __builtin_amdgcn_sched_barrier(0); \
} while (0)

// ---------------------------------------------------------------------------
// Transpose (C,H,W) fp32 -> (H,W,C) fp16 (interleaved 32B texels).
// ---------------------------------------------------------------------------
__global__ __launch_bounds__(256) void transpose_chw_hwc_h(
    const float* __restrict__ p0, const float* __restrict__ p1,
    const float* __restrict__ p2, __half* __restrict__ dst)
{
    __shared__ float lds[64 * 17];
    const int y  = blockIdx.x;
    const int x0 = blockIdx.y * 64;
    const int pl = blockIdx.z;
    const float* src = (pl == 0) ? p0 : ((pl == 1) ? p1 : p2);
    const int tid = threadIdx.x;
    const int xl  = tid & 63;
    const int c0  = tid >> 6;
#pragma unroll
    for (int i = 0; i < 4; ++i) {
        const int c = c0 * 4 + i;
        lds[xl * 17 + c] = src[c * HW + y * R + x0 + xl];
    }
    __syncthreads();
    __half2* dbase = (__half2*)(dst + ((size_t)pl * HW + (size_t)(y * R + x0)) * C);
#pragma unroll
    for (int i = 0; i < 2; ++i) {
        const int j  = tid + i * 256;
        const int e0 = 2 * j;
        const float a = lds[(e0 >> 4) * 17 + (e0 & 15)];
        const float b = lds[(e0 >> 4) * 17 + ((e0 & 15) + 1)];
        dbase[j] = __floats2half2_rn(a, b);
    }
}

// ---------------------------------------------------------------------------
// Coarse histogram (9-bit) with LDS aggregation.
// ---------------------------------------------------------------------------
__global__ __launch_bounds__(256) void hist_pts(
    const float* __restrict__ x, unsigned int* __restrict__ counts, int B)
{
    __shared__ unsigned int h[NB9];
    const int tid = threadIdx.x;
    for (int i = tid; i < NB9; i += 256) h[i] = 0;
    __syncthreads();
    const int start = blockIdx.x * CHUNK;
#pragma unroll
    for (int j = 0; j < CHUNK / 256; ++j) {
        const int i = start + j * 256 + tid;
        if (i < B) {
            const float a = x[(size_t)i * 3 + 0];
            const float b = x[(size_t)i * 3 + 1];
            const float c = x[(size_t)i * 3 + 2];
            atomicAdd(&h[key9(a, b, c)], 1u);
        }
    }
    __syncthreads();
    unsigned int* cb = counts + (blockIdx.x & (NPART - 1)) * NB9;
    for (int i = tid; i < NB9; i += 256) {
        const unsigned int c = h[i];
        if (c) atomicAdd(&cb[i], c);
    }
}

// Scan 4096 coarse counters in LOGICAL (key,part) order (records bin-major);
// counters part-major in memory. Emits binStart[key].
__global__ __launch_bounds__(1024) void scan_counts(
    const unsigned int* __restrict__ counts, unsigned int* __restrict__ cursor,
    unsigned int* __restrict__ binStart)
{
    __shared__ unsigned int s[1024];
    const int t = threadIdx.x;
    unsigned int v[4];
    unsigned int sum = 0;
#pragma unroll
    for (int i = 0; i < 4; ++i) {
        const int L = t * 4 + i;            // logical = key*NPART + part
        const int key = L >> 3, part = L & 7;
        v[i] = counts[part * NB9 + key];
        sum += v[i];
    }
    unsigned int run = 0;
#pragma unroll
    for (int i = 0; i < 4; ++i) { const unsigned int tmp = v[i]; v[i] = run; run += tmp; }
    s[t] = sum;
    __syncthreads();
    unsigned int incl = sum;
    for (int off = 1; off < 1024; off <<= 1) {
        const unsigned int u = (t >= off) ? s[t - off] : 0u;
        __syncthreads();
        incl += u;
        s[t] = incl;
        __syncthreads();
    }
    const unsigned int excl = incl - sum;
#pragma unroll
    for (int i = 0; i < 4; ++i) {
        const int L = t * 4 + i;
        const int key = L >> 3, part = L & 7;
        cursor[part * NB9 + key] = excl + v[i];
        if (part == 0) binStart[key] = excl + v[i];
    }
    if (t == 1023) binStart[NB9] = incl;    // = B
}

// ---------------------------------------------------------------------------
// Coarse scatter: block-local counting sort (bin-sorted, run-coalesced writes).
// ---------------------------------------------------------------------------
__global__ __launch_bounds__(256) void scatter_pts(
    const float* __restrict__ x, unsigned int* __restrict__ cursor,
    int4* __restrict__ recs, int B)
{
    __shared__ unsigned int h[NB9];
    __shared__ unsigned int gbase[NB9];
    __shared__ unsigned int lpre[NB9];
    __shared__ unsigned int lcur[NB9];
    __shared__ int4 buf[CHUNK];
    __shared__ unsigned short binOf[CHUNK];

    const int tid   = threadIdx.x;
    const int start = blockIdx.x * CHUNK;
    const int V     = min(CHUNK, B - start);

    for (int i = tid; i < NB9; i += 256) h[i] = 0;
    __syncthreads();

    float pa[CHUNK / 256], pb_[CHUNK / 256], pc[CHUNK / 256];
    unsigned int pk[CHUNK / 256];
#pragma unroll
    for (int j = 0; j < CHUNK / 256; ++j) {
        const int i = start + j * 256 + tid;
        pk[j] = 0xFFFFFFFFu;
        if (i < B) {
            pa[j] = x[(size_t)i * 3 + 0];
            pb_[j] = x[(size_t)i * 3 + 1];
            pc[j] = x[(size_t)i * 3 + 2];
            pk[j] = key9(pa[j], pb_[j], pc[j]);
            atomicAdd(&h[pk[j]], 1u);
        }
    }
    __syncthreads();

    unsigned int* cb = cursor + (blockIdx.x & (NPART - 1)) * NB9;
    for (int b = tid; b < NB9; b += 256) {
        const unsigned int c = h[b];
        gbase[b] = c ? atomicAdd(&cb[b], c) : 0u;
    }
    if (tid < 64) {
        unsigned int loc[8];
        unsigned int tot = 0;
#pragma unroll
        for (int j = 0; j < 8; ++j) { loc[j] = h[tid * 8 + j]; tot += loc[j]; }
        unsigned int run = tot;
#pragma unroll
        for (int d = 1; d < 64; d <<= 1) {
            const unsigned int u = __shfl_up(run, (unsigned)d, 64);
            if (tid >= d) run += u;
        }
        unsigned int excl = run - tot;
#pragma unroll
        for (int j = 0; j < 8; ++j) { lpre[tid * 8 + j] = excl; excl += loc[j]; }
    }
    __syncthreads();
    for (int b = tid; b < NB9; b += 256) lcur[b] = lpre[b];
    __syncthreads();

#pragma unroll
    for (int j = 0; j < CHUNK / 256; ++j) {
        if (pk[j] != 0xFFFFFFFFu) {
            const int i = start + j * 256 + tid;
            const unsigned int rk = atomicAdd(&lcur[pk[j]], 1u);
            buf[rk] = make_int4(__float_as_int(pa[j]), __float_as_int(pb_[j]),
                                __float_as_int(pc[j]), i);
            binOf[rk] = (unsigned short)pk[j];
        }
    }
    __syncthreads();

    for (int idx = tid; idx < V; idx += 256) {
        const int4 rc = buf[idx];
        const int  k  = binOf[idx];
        const unsigned int dest = gbase[k] + ((unsigned int)idx - lpre[k]);
        const v4i rv = { rc.x, rc.y, rc.z, rc.w };
        __builtin_nontemporal_store(rv, (v4i*)&recs[dest]);
    }
}

// ---------------------------------------------------------------------------
// FUSED refine+sample: one block per coarse bin (XCD-chunked: XCD j owns
// Morton octant j). Phase 1: rank the bin's records by the 6 fine Morton
// bits (LDS hist + register keys, = old refine) and write a 2B order[]
// permutation to LDS. Phase 2: round-13 forced-MLP gather body, walking
// records through order[] (fine-Morton traversal -> L1-sized gather window).
// Bins beyond KCAP fall back to unsorted processing of the tail (correct
// for any input; never triggered for uniform points).
// ---------------------------------------------------------------------------
__global__ __launch_bounds__(512) void sample_bin(
    const int4* __restrict__ recs, const __half* __restrict__ t,
    const unsigned int* __restrict__ binStart,
    float* __restrict__ out, int B)
{
    __shared__ unsigned int hh[64];
    __shared__ unsigned int pre[64];
    __shared__ unsigned short order[KCAP];

    const unsigned int bid = blockIdx.x;
    const int k = (int)((bid & 7u) * (NB9 / 8u) + (bid >> 3));  // XCD-chunked
    const unsigned int s0 = binStart[k];
    const unsigned int s1 = binStart[k + 1];
    const int n = (int)(s1 - s0);
    if (n <= 0) return;
    const int ns = min(n, KCAP);
    const int tid = threadIdx.x;

    if (tid < 64) hh[tid] = 0;
    __syncthreads();

    // ---- phase 1: rank by fine 6-bit Morton subkey ----
    unsigned int rs[KMX];                    // (rank<<6)|sub
#pragma unroll
    for (int j = 0; j < KMX; ++j) {
        const int idx = tid + j * 512;
        rs[j] = 0xFFFFFFFFu;
        if (idx < ns) {
            const v4i rc = *(const v4i*)&recs[s0 + idx];
            const int c0 = cell512(__int_as_float(rc.x)) >> 4;
            const int c1 = cell512(__int_as_float(rc.y)) >> 4;
            const int c2 = cell512(__int_as_float(rc.z)) >> 4;
            const unsigned int sub = mortonN(c0, c1, c2, 5) & 63u;
            const unsigned int rank = atomicAdd(&hh[sub], 1u);
            rs[j] = (rank << 6) | sub;
        }
    }
    __syncthreads();

    if (tid < 64) {
        const unsigned int v = hh[tid];
        unsigned int run = v;
#pragma unroll
        for (int d = 1; d < 64; d <<= 1) {
            const unsigned int u = __shfl_up(run, (unsigned)d, 64);
            if (tid >= d) run += u;
        }
        pre[tid] = run - v;
    }
    __syncthreads();

#pragma unroll
    for (int j = 0; j < KMX; ++j) {
        if (rs[j] != 0xFFFFFFFFu) {
            const unsigned int sub  = rs[j] & 63u;
            const unsigned int rank = rs[j] >> 6;
            order[pre[sub] + rank] = (unsigned short)(tid + j * 512);
        }
    }
    __syncthreads();

    // ---- phase 2: sample in fine order; 2 lanes/pt (8 channels each) ----
    for (int s2 = tid; s2 < 2 * n; s2 += 512) {
        const int sp = s2 >> 1;
        const int h  = s2 & 1;
        const int ri = (sp < ns) ? (int)order[sp] : sp;   // tail: unsorted
        const v4i rec = *(const v4i*)&recs[s0 + ri];
        const float xv0 = __int_as_float(rec.x);
        const float xv1 = __int_as_float(rec.y);
        const float xv2 = __int_as_float(rec.z);

        float w[3][4];
        uint32_t off[3][4];
        const uint32_t hofs = (uint32_t)h * 16u;
#pragma unroll
        for (int pl = 0; pl < 3; ++pl) {
            const float gx = (pl == 2) ? xv1 : xv0;
            const float gy = (pl == 0) ? xv1 : xv2;
            const float px = (gx + 1.0f) * 0.5f * (float)(R - 1);
            const float py = (gy + 1.0f) * 0.5f * (float)(R - 1);
            const float x0f = floorf(px), y0f = floorf(py);
            const float wx = px - x0f,   wy = py - y0f;
            int x0 = (int)x0f; x0 = min(max(x0, 0), R - 1);
            int y0 = (int)y0f; y0 = min(max(y0, 0), R - 1);
            const int x1 = min(x0 + 1, R - 1);
            const int y1 = min(y0 + 1, R - 1);
            off[pl][0] = ((uint32_t)(y0 * R) + (uint32_t)x0) * 32u + hofs;
            off[pl][1] = ((uint32_t)(y0 * R) + (uint32_t)x1) * 32u + hofs;
            off[pl][2] = ((uint32_t)(y1 * R) + (uint32_t)x0) * 32u + hofs;
            off[pl][3] = ((uint32_t)(y1 * R) + (uint32_t)x1) * 32u + hofs;
            w[pl][0] = (1.f - wx) * (1.f - wy);
            w[pl][1] = wx * (1.f - wy);
            w[pl][2] = (1.f - wx) * wy;
            w[pl][3] = wx * wy;
        }

        v4i raw[3][4];
#pragma unroll
        for (int pl = 0; pl < 3; ++pl) {
            const void* pb = (const char*)t + (size_t)pl * ((size_t)HW * C * 2);
#pragma unroll
            for (int c2 = 0; c2 < 4; ++c2)
                raw[pl][c2] = gload16(pb, off[pl][c2]);
        }

        float acc[8] = {1.f, 1.f, 1.f, 1.f, 1.f, 1.f, 1.f, 1.f};
#pragma unroll
        for (int pl = 0; pl < 3; ++pl) {
            if (pl == 0) VMWAIT(8);
            else if (pl == 1) VMWAIT(4);
            else VMWAIT(0);
            const __half2* f0 = (const __half2*)&raw[pl][0];
            const __half2* f1 = (const __half2*)&raw[pl][1];
            const __half2* f2 = (const __half2*)&raw[pl][2];
            const __half2* f3 = (const __half2*)&raw[pl][3];
            const float w00 = w[pl][0], w01 = w[pl][1];
            const float w10 = w[pl][2], w11 = w[pl][3];
#pragma unroll
            for (int i2 = 0; i2 < 4; ++i2) {
                const float2 a0 = __half22float2(f0[i2]);
                const float2 a1 = __half22float2(f1[i2]);
                const float2 a2 = __half22float2(f2[i2]);
                const float2 a3 = __half22float2(f3[i2]);
                acc[2 * i2 + 0] *= a0.x * w00 + a1.x * w01 + a2.x * w10 + a3.x * w11;
                acc[2 * i2 + 1] *= a0.y * w00 + a1.y * w01 + a2.y * w10 + a3.y * w11;
            }
        }

        float* o = out + (size_t)rec.w * C + h * 8;
        const v4f o0 = { acc[0], acc[1], acc[2], acc[3] };
        const v4f o1 = { acc[4], acc[5], acc[6], acc[7] };
        __builtin_nontemporal_store(o0, (v4f*)(o + 0));
        __builtin_nontemporal_store(o1, (v4f*)(o + 4));
    }
}

// ============================ fallback paths ================================
__global__ __launch_bounds__(256) void transpose_chw_hwc(
    const float* __restrict__ p0, const float* __restrict__ p1,
    const float* __restrict__ p2, float* __restrict__ dst)
{
    __shared__ float lds[64 * 17];
    const int y  = blockIdx.x;
    const int x0 = blockIdx.y * 64;
    const int pl = blockIdx.z;
    const float* src = (pl == 0) ? p0 : ((pl == 1) ? p1 : p2);
    const int tid = threadIdx.x;
    const int xl  = tid & 63;
    const int c0  = tid >> 6;
#pragma unroll
    for (int i = 0; i < 4; ++i) {
        const int c = c0 * 4 + i;
        lds[xl * 17 + c] = src[c * HW + y * R + x0 + xl];
    }
    __syncthreads();
    float* dbase = dst + ((size_t)pl * HW + (size_t)(y * R + x0)) * C;
#pragma unroll
    for (int i = 0; i < 4; ++i) {
        const int j = tid + i * 256;
        dbase[j] = lds[(j >> 4) * 17 + (j & 15)];
    }
}

__global__ __launch_bounds__(256) void sample_hwc(
    const float* __restrict__ x, const float* __restrict__ t,
    float* __restrict__ out, int B)
{
    const int tid = blockIdx.x * 256 + threadIdx.x;
    const int p   = tid >> 2;
    const int cg  = tid & 3;
    if (p >= B) return;

    const float xv0 = x[(size_t)p * 3 + 0];
    const float xv1 = x[(size_t)p * 3 + 1];
    const float xv2 = x[(size_t)p * 3 + 2];
    const float gxs[3] = { xv0, xv0, xv1 };
    const float gys[3] = { xv1, xv2, xv2 };
    float4 acc = make_float4(1.f, 1.f, 1.f, 1.f);

#pragma unroll
    for (int pl = 0; pl < 3; ++pl) {
        const float gx = gxs[pl], gy = gys[pl];
        const float px = (gx + 1.0f) * 0.5f * (float)(R - 1);
        const float py = (gy + 1.0f) * 0.5f * (float)(R - 1);
        const float x0f = floorf(px), y0f = floorf(py);
        const float wx = px - x0f,   wy = py - y0f;
        int x0 = (int)x0f; x0 = min(max(x0, 0), R - 1);
        int y0 = (int)y0f; y0 = min(max(y0, 0), R - 1);
        const int x1 = min(x0 + 1, R - 1);
        const int y1 = min(y0 + 1, R - 1);

        const float* pb = t + (size_t)pl * (size_t)(HW * C) + cg * 4;
        const float4 p00 = *(const float4*)(pb + (size_t)(y0 * R + x0) * C);
        const float4 p01 = *(const float4*)(pb + (size_t)(y0 * R + x1) * C);
        const float4 p10 = *(const float4*)(pb + (size_t)(y1 * R + x0) * C);
        const float4 p11 = *(const float4*)(pb + (size_t)(y1 * R + x1) * C);

        const float w00 = (1.f - wx) * (1.f - wy);
        const float w01 = wx * (1.f - wy);
        const float w10 = (1.f - wx) * wy;
        const float w11 = wx * wy;

        float4 fv;
        fv.x = p00.x * w00 + p01.x * w01 + p10.x * w10 + p11.x * w11;
        fv.y = p00.y * w00 + p01.y * w01 + p10.y * w10 + p11.y * w11;
        fv.z = p00.z * w00 + p01.z * w01 + p10.z * w10 + p11.z * w11;
        fv.w = p00.w * w00 + p01.w * w01 + p10.w * w10 + p11.w * w11;

        acc.x *= fv.x; acc.y *= fv.y; acc.z *= fv.z; acc.w *= fv.w;
    }

    *(float4*)(out + (size_t)p * C + cg * 4) = acc;
}

__global__ __launch_bounds__(256) void sample_chw(
    const float* __restrict__ x,
    const float* __restrict__ p0, const float* __restrict__ p1,
    const float* __restrict__ p2, float* __restrict__ out, int B)
{
    const int tid = blockIdx.x * 256 + threadIdx.x;
    const int p   = tid >> 2;
    const int cg  = tid & 3;
    if (p >= B) return;
    const float xv0 = x[(size_t)p * 3 + 0];
    const float xv1 = x[(size_t)p * 3 + 1];
    const float xv2 = x[(size_t)p * 3 + 2];
    const float gxs[3] = { xv0, xv0, xv1 };
    const float gys[3] = { xv1, xv2, xv2 };
    const float* planes[3] = { p0, p1, p2 };
    float acc[4] = {1.f, 1.f, 1.f, 1.f};
#pragma unroll
    for (int pl = 0; pl < 3; ++pl) {
        const float gx = gxs[pl], gy = gys[pl];
        const float px = (gx + 1.0f) * 0.5f * (float)(R - 1);
        const float py = (gy + 1.0f) * 0.5f * (float)(R - 1);
        const float x0f = floorf(px), y0f = floorf(py);
        const float wx = px - x0f,   wy = py - y0f;
        int x0 = (int)x0f; x0 = min(max(x0, 0), R - 1);
        int y0 = (int)y0f; y0 = min(max(y0, 0), R - 1);
        const int x1 = min(x0 + 1, R - 1);
        const int y1 = min(y0 + 1, R - 1);
        const float w00 = (1.f - wx) * (1.f - wy);
        const float w01 = wx * (1.f - wy);
        const float w10 = (1.f - wx) * wy;
        const float w11 = wx * wy;
        const float* pb = planes[pl];
#pragma unroll
        for (int k = 0; k < 4; ++k) {
            const int c = cg * 4 + k;
            const float* b2 = pb + (size_t)c * HW;
            const float v00 = b2[y0 * R + x0];
            const float v01 = b2[y0 * R + x1];
            const float v10 = b2[y1 * R + x0];
            const float v11 = b2[y1 * R + x1];
            acc[k] *= v00 * w00 + v01 * w01 + v10 * w10 + v11 * w11;
        }
    }
    float* o = out + (size_t)p * C + cg * 4;
    o[0] = acc[0]; o[1] = acc[1]; o[2] = acc[2]; o[3] = acc[3];
}

// ===========================================================================
extern "C" void kernel_launch(void* const* d_in, const int* in_sizes, int n_in,
                              void* d_out, int out_size, void* d_ws, size_t ws_size,
                              hipStream_t stream) {
    const float* x  = (const float*)d_in[0];
    const float* p0 = (const float*)d_in[1];
    const float* p1 = (const float*)d_in[2];
    const float* p2 = (const float*)d_in[3];
    float* out = (float*)d_out;
    const int B = in_sizes[0] / 3;

    const size_t t_bytes    = (size_t)3 * HW * C * sizeof(__half);     // 24 MiB
    const size_t recs_bytes = (size_t)B * 16;                          // 32 MB
    const size_t cnt_bytes  = (size_t)NCNT * 4;                        // 16 KiB
    const size_t bs_bytes   = (size_t)(NB9 + 1) * 4;

    const size_t off_t      = 0;
    const size_t off_recs   = (t_bytes + 255) & ~(size_t)255;
    const size_t off_counts = (off_recs + recs_bytes + 255) & ~(size_t)255;
    const size_t off_cursor = (off_counts + cnt_bytes + 255) & ~(size_t)255;
    const size_t off_bs     = (off_cursor + cnt_bytes + 255) & ~(size_t)255;
    const size_t need_full  = off_bs + bs_bytes;

    const size_t need_fp32  = (size_t)3 * HW * C * sizeof(float);      // 48 MiB

    if (d_ws != nullptr && ws_size >= need_full) {
        __half*       t      = (__half*)((char*)d_ws + off_t);
        int4*         recs   = (int4*)((char*)d_ws + off_recs);
        unsigned int* counts = (unsigned int*)((char*)d_ws + off_counts);
        unsigned int* cursor = (unsigned int*)((char*)d_ws + off_cursor);
        unsigned int* bstart = (unsigned int*)((char*)d_ws + off_bs);

        dim3 tg(R, R / 64, 3);
        transpose_chw_hwc_h<<<tg, 256, 0, stream>>>(p0, p1, p2, t);

        hipMemsetAsync(counts, 0, cnt_bytes, stream);
        const int nblkP = (B + CHUNK - 1) / CHUNK;
        hist_pts<<<nblkP, 256, 0, stream>>>(x, counts, B);
        scan_counts<<<1, 1024, 0, stream>>>(counts, cursor, bstart);
        scatter_pts<<<nblkP, 256, 0, stream>>>(x, cursor, recs, B);

        sample_bin<<<NB9, 512, 0, stream>>>(recs, t, bstart, out, B);
    } else if (d_ws != nullptr && ws_size >= need_fp32) {
        float* tf = (float*)d_ws;
        dim3 tg(R, R / 64, 3);
        transpose_chw_hwc<<<tg, 256, 0, stream>>>(p0, p1, p2, tf);
        const int nthr = B * 4;
        const int nblk = (nthr + 255) / 256;
        sample_hwc<<<nblk, 256, 0, stream>>>(x, tf, out, B);
    } else {
        const int nthr = B * 4;
        const int nblk = (nthr + 255) / 256;
        sample_chw<<<nblk, 256, 0, stream>>>(x, p0, p1, p2, out, B);
    }
}

// Round 15
// 137.117 us; speedup vs baseline: 1.0674x; 1.0674x over previous
//
#include <hip/hip_runtime.h>
#include <hip/hip_fp16.h>
#include <cstdint>
#include <cstddef>

constexpr int R  = 512;
constexpr int C  = 16;
constexpr int HW = R * R;

constexpr int NB9   = 512;    // coarse bins: 3 bits/axis (64px cells)
constexpr int NPART = 8;      // XCD partitions for coarse counters
constexpr int NCNT  = NB9 * NPART;
constexpr int CHUNK = 4096;   // pts/block in hist/scatter
constexpr int KMAX  = 16;     // refine: recs per thread (cap 8192 per coarse bin)
constexpr int NSUB  = 512;    // refine sub-bins: 3 more bits/axis (8px cells)

typedef float v4f __attribute__((ext_vector_type(4)));
typedef int   v4i __attribute__((ext_vector_type(4)));

// ---- unified, bit-exact coordinate helpers ----------
__device__ __forceinline__ float tcoord(float g) {
    return __fmul_rn(__fadd_rn(g, 1.0f), 255.5f);   // bit-exact == ((g+1)*0.5f)*511
}
__device__ __forceinline__ int cell512(float g) {
    const int i = (int)tcoord(g);
    return min(max(i, 0), R - 1);
}
__device__ __forceinline__ uint32_t mortonN(int a, int b, int c, int nb) {
    uint32_t k = 0;
#pragma unroll
    for (int i = 0; i < 5; ++i) {
        if (i < nb) {
            k |= ((uint32_t)((a >> i) & 1)) << (3 * i + 2);
            k |= ((uint32_t)((b >> i) & 1)) << (3 * i + 1);
            k |= ((uint32_t)((c >> i) & 1)) << (3 * i + 0);
        }
    }
    return k;
}
__device__ __forceinline__ uint32_t key9(float a, float b, float c) {
    return mortonN(cell512(a) >> 6, cell512(b) >> 6, cell512(c) >> 6, 3);
}

// ---- forced-MLP gather primitives (inline asm, SADDR + 32-bit voffset) ----
__device__ __forceinline__ v4i gload16(const void* base, uint32_t voff) {
    v4i r;
    asm volatile("global_load_dwordx4 %0, %1, %2"
                 : "=&v"(r) : "v"(voff), "s"(base));
    return r;
}
#define VMWAIT(N) do { \
    asm volatile("s_waitcnt vmcnt(" #N ")" ::: "memory"); \
    __builtin_amdgcn_sched_barrier(0); \
} while (0)

// ---------------------------------------------------------------------------
// Transpose (C,H,W) fp32 -> (H,W,C) fp16 (interleaved 32B texels).
// ---------------------------------------------------------------------------
__global__ __launch_bounds__(256) void transpose_chw_hwc_h(
    const float* __restrict__ p0, const float* __restrict__ p1,
    const float* __restrict__ p2, __half* __restrict__ dst)
{
    __shared__ float lds[64 * 17];
    const int y  = blockIdx.x;
    const int x0 = blockIdx.y * 64;
    const int pl = blockIdx.z;
    const float* src = (pl == 0) ? p0 : ((pl == 1) ? p1 : p2);
    const int tid = threadIdx.x;
    const int xl  = tid & 63;
    const int c0  = tid >> 6;
#pragma unroll
    for (int i = 0; i < 4; ++i) {
        const int c = c0 * 4 + i;
        lds[xl * 17 + c] = src[c * HW + y * R + x0 + xl];
    }
    __syncthreads();
    __half2* dbase = (__half2*)(dst + ((size_t)pl * HW + (size_t)(y * R + x0)) * C);
#pragma unroll
    for (int i = 0; i < 2; ++i) {
        const int j  = tid + i * 256;
        const int e0 = 2 * j;
        const float a = lds[(e0 >> 4) * 17 + (e0 & 15)];
        const float b = lds[(e0 >> 4) * 17 + ((e0 & 15) + 1)];
        dbase[j] = __floats2half2_rn(a, b);
    }
}

// ---------------------------------------------------------------------------
// Coarse histogram (9-bit) with LDS aggregation.
// ---------------------------------------------------------------------------
__global__ __launch_bounds__(256) void hist_pts(
    const float* __restrict__ x, unsigned int* __restrict__ counts, int B)
{
    __shared__ unsigned int h[NB9];
    const int tid = threadIdx.x;
    for (int i = tid; i < NB9; i += 256) h[i] = 0;
    __syncthreads();
    const int start = blockIdx.x * CHUNK;
#pragma unroll
    for (int j = 0; j < CHUNK / 256; ++j) {
        const int i = start + j * 256 + tid;
        if (i < B) {
            const float a = x[(size_t)i * 3 + 0];
            const float b = x[(size_t)i * 3 + 1];
            const float c = x[(size_t)i * 3 + 2];
            atomicAdd(&h[key9(a, b, c)], 1u);
        }
    }
    __syncthreads();
    unsigned int* cb = counts + (blockIdx.x & (NPART - 1)) * NB9;
    for (int i = tid; i < NB9; i += 256) {
        const unsigned int c = h[i];
        if (c) atomicAdd(&cb[i], c);
    }
}

// Scan 4096 coarse counters in LOGICAL (key,part) order (records bin-major);
// counters part-major in memory. Emits binStart[key] for refine.
__global__ __launch_bounds__(1024) void scan_counts(
    const unsigned int* __restrict__ counts, unsigned int* __restrict__ cursor,
    unsigned int* __restrict__ binStart)
{
    __shared__ unsigned int s[1024];
    const int t = threadIdx.x;
    unsigned int v[4];
    unsigned int sum = 0;
#pragma unroll
    for (int i = 0; i < 4; ++i) {
        const int L = t * 4 + i;            // logical = key*NPART + part
        const int key = L >> 3, part = L & 7;
        v[i] = counts[part * NB9 + key];
        sum += v[i];
    }
    unsigned int run = 0;
#pragma unroll
    for (int i = 0; i < 4; ++i) { const unsigned int tmp = v[i]; v[i] = run; run += tmp; }
    s[t] = sum;
    __syncthreads();
    unsigned int incl = sum;
    for (int off = 1; off < 1024; off <<= 1) {
        const unsigned int u = (t >= off) ? s[t - off] : 0u;
        __syncthreads();
        incl += u;
        s[t] = incl;
        __syncthreads();
    }
    const unsigned int excl = incl - sum;
#pragma unroll
    for (int i = 0; i < 4; ++i) {
        const int L = t * 4 + i;
        const int key = L >> 3, part = L & 7;
        cursor[part * NB9 + key] = excl + v[i];
        if (part == 0) binStart[key] = excl + v[i];
    }
    if (t == 1023) binStart[NB9] = incl;    // = B
}

// ---------------------------------------------------------------------------
// Coarse scatter: block-local counting sort (bin-sorted, run-coalesced writes).
// ---------------------------------------------------------------------------
__global__ __launch_bounds__(256) void scatter_pts(
    const float* __restrict__ x, unsigned int* __restrict__ cursor,
    int4* __restrict__ recs, int B)
{
    __shared__ unsigned int h[NB9];
    __shared__ unsigned int gbase[NB9];
    __shared__ unsigned int lpre[NB9];
    __shared__ unsigned int lcur[NB9];
    __shared__ int4 buf[CHUNK];
    __shared__ unsigned short binOf[CHUNK];

    const int tid   = threadIdx.x;
    const int start = blockIdx.x * CHUNK;
    const int V     = min(CHUNK, B - start);

    for (int i = tid; i < NB9; i += 256) h[i] = 0;
    __syncthreads();

    float pa[CHUNK / 256], pb_[CHUNK / 256], pc[CHUNK / 256];
    unsigned int pk[CHUNK / 256];
#pragma unroll
    for (int j = 0; j < CHUNK / 256; ++j) {
        const int i = start + j * 256 + tid;
        pk[j] = 0xFFFFFFFFu;
        if (i < B) {
            pa[j] = x[(size_t)i * 3 + 0];
            pb_[j] = x[(size_t)i * 3 + 1];
            pc[j] = x[(size_t)i * 3 + 2];
            pk[j] = key9(pa[j], pb_[j], pc[j]);
            atomicAdd(&h[pk[j]], 1u);
        }
    }
    __syncthreads();

    unsigned int* cb = cursor + (blockIdx.x & (NPART - 1)) * NB9;
    for (int b = tid; b < NB9; b += 256) {
        const unsigned int c = h[b];
        gbase[b] = c ? atomicAdd(&cb[b], c) : 0u;
    }
    if (tid < 64) {
        unsigned int loc[8];
        unsigned int tot = 0;
#pragma unroll
        for (int j = 0; j < 8; ++j) { loc[j] = h[tid * 8 + j]; tot += loc[j]; }
        unsigned int run = tot;
#pragma unroll
        for (int d = 1; d < 64; d <<= 1) {
            const unsigned int u = __shfl_up(run, (unsigned)d, 64);
            if (tid >= d) run += u;
        }
        unsigned int excl = run - tot;
#pragma unroll
        for (int j = 0; j < 8; ++j) { lpre[tid * 8 + j] = excl; excl += loc[j]; }
    }
    __syncthreads();
    for (int b = tid; b < NB9; b += 256) lcur[b] = lpre[b];
    __syncthreads();

#pragma unroll
    for (int j = 0; j < CHUNK / 256; ++j) {
        if (pk[j] != 0xFFFFFFFFu) {
            const int i = start + j * 256 + tid;
            const unsigned int rk = atomicAdd(&lcur[pk[j]], 1u);
            buf[rk] = make_int4(__float_as_int(pa[j]), __float_as_int(pb_[j]),
                                __float_as_int(pc[j]), i);
            binOf[rk] = (unsigned short)pk[j];
        }
    }
    __syncthreads();

    for (int idx = tid; idx < V; idx += 256) {
        const int4 rc = buf[idx];
        const int  k  = binOf[idx];
        const unsigned int dest = gbase[k] + ((unsigned int)idx - lpre[k]);
        const v4i rv = { rc.x, rc.y, rc.z, rc.w };
        __builtin_nontemporal_store(rv, (v4i*)&recs[dest]);
    }
}

// ---------------------------------------------------------------------------
// Refine: in-place permutation of each coarse bin's records by the 9 finer
// Morton bits (8px cells) -> overall 18-bit Morton order. The 3-plane gather
// window of an 8px cell is ~10KB (vs 31KB at 16px) -> comfortably L1-resident
// for the sampler. Records held in registers across the barrier; one block
// per coarse bin; sampler streams recs linearly (no index table).
// ---------------------------------------------------------------------------
__global__ __launch_bounds__(512) void refine_pts(
    const unsigned int* __restrict__ binStart, int4* __restrict__ recs)
{
    __shared__ unsigned int h[NSUB];
    __shared__ unsigned int pre[NSUB];
    const int k = blockIdx.x;
    const unsigned int s0 = binStart[k];
    const unsigned int s1 = binStart[k + 1];
    const int tid = threadIdx.x;
    if (tid < NSUB) h[tid] = 0;
    __syncthreads();

    int4 rc[KMAX];
    unsigned int rs[KMAX];                  // (rank<<9)|sub
#pragma unroll
    for (int j = 0; j < KMAX; ++j) {
        const unsigned int idx = s0 + (unsigned)tid + (unsigned)j * 512u;
        rs[j] = 0xFFFFFFFFu;
        if (idx < s1) {
            rc[j] = recs[idx];
            const int f0 = (cell512(__int_as_float(rc[j].x)) >> 3) & 7;
            const int f1 = (cell512(__int_as_float(rc[j].y)) >> 3) & 7;
            const int f2 = (cell512(__int_as_float(rc[j].z)) >> 3) & 7;
            const unsigned int sub = mortonN(f0, f1, f2, 3);   // 9 bits
            const unsigned int rank = atomicAdd(&h[sub], 1u);
            rs[j] = (rank << 9) | sub;
        }
    }
    __syncthreads();

    // exclusive prefix over 512 sub-bins: wave 0, 8 bins/lane + wave scan
    if (tid < 64) {
        unsigned int loc[8];
        unsigned int tot = 0;
#pragma unroll
        for (int j = 0; j < 8; ++j) { loc[j] = h[tid * 8 + j]; tot += loc[j]; }
        unsigned int run = tot;
#pragma unroll
        for (int d = 1; d < 64; d <<= 1) {
            const unsigned int u = __shfl_up(run, (unsigned)d, 64);
            if (tid >= d) run += u;
        }
        unsigned int excl = run - tot;
#pragma unroll
        for (int j = 0; j < 8; ++j) { pre[tid * 8 + j] = excl; excl += loc[j]; }
    }
    __syncthreads();

#pragma unroll
    for (int j = 0; j < KMAX; ++j) {
        if (rs[j] != 0xFFFFFFFFu) {
            const unsigned int sub  = rs[j] & 511u;
            const unsigned int rank = rs[j] >> 9;
            recs[s0 + pre[sub] + rank] = rc[j];
        }
    }
}

// ---------------------------------------------------------------------------
// Sampler, forced-MLP, 1 point per thread (2 lanes/pt, 8 channels per lane):
// 12 inline-asm global_load_dwordx4 issued back-to-back, consumed per-plane
// behind counted s_waitcnt vmcnt(8/4/0) + sched_barrier (guide rule #18).
// ---------------------------------------------------------------------------
__global__ __launch_bounds__(256) void sample_sorted(
    const int4* __restrict__ recs, const __half* __restrict__ t,
    float* __restrict__ out, int B, int q, int r)
{
    const uint32_t bid  = blockIdx.x;
    const uint32_t xcd  = bid & 7u;
    const uint32_t slot = bid >> 3;
    const uint32_t base = (xcd < (uint32_t)r) ? xcd * (q + 1)
                                              : (uint32_t)r * (q + 1) + (xcd - r) * q;
    const uint32_t lb   = base + slot;

    const int tid = (int)(lb * 256u + threadIdx.x);
    const int p   = tid >> 1;
    const int h   = tid & 1;
    if (p >= B) return;

    const v4i rec = __builtin_nontemporal_load((const v4i*)&recs[p]);
    const float xv0 = __int_as_float(rec.x);
    const float xv1 = __int_as_float(rec.y);
    const float xv2 = __int_as_float(rec.z);

    // ---- coordinate math: weights + 12 byte offsets (32-bit) ----
    float w[3][4];
    uint32_t off[3][4];
    const uint32_t hofs = (uint32_t)h * 16u;
#pragma unroll
    for (int pl = 0; pl < 3; ++pl) {
        const float gx = (pl == 2) ? xv1 : xv0;
        const float gy = (pl == 0) ? xv1 : xv2;
        const float px = (gx + 1.0f) * 0.5f * (float)(R - 1);
        const float py = (gy + 1.0f) * 0.5f * (float)(R - 1);
        const float x0f = floorf(px), y0f = floorf(py);
        const float wx = px - x0f,   wy = py - y0f;
        int x0 = (int)x0f; x0 = min(max(x0, 0), R - 1);
        int y0 = (int)y0f; y0 = min(max(y0, 0), R - 1);
        const int x1 = min(x0 + 1, R - 1);
        const int y1 = min(y0 + 1, R - 1);
        off[pl][0] = ((uint32_t)(y0 * R) + (uint32_t)x0) * 32u + hofs;
        off[pl][1] = ((uint32_t)(y0 * R) + (uint32_t)x1) * 32u + hofs;
        off[pl][2] = ((uint32_t)(y1 * R) + (uint32_t)x0) * 32u + hofs;
        off[pl][3] = ((uint32_t)(y1 * R) + (uint32_t)x1) * 32u + hofs;
        w[pl][0] = (1.f - wx) * (1.f - wy);
        w[pl][1] = wx * (1.f - wy);
        w[pl][2] = (1.f - wx) * wy;
        w[pl][3] = wx * wy;
    }

    // ---- issue ALL 12 loads (volatile asm: order pinned, cannot sink) ----
    v4i raw[3][4];
#pragma unroll
    for (int pl = 0; pl < 3; ++pl) {
        const void* pb = (const char*)t + (size_t)pl * ((size_t)HW * C * 2);
#pragma unroll
        for (int c2 = 0; c2 < 4; ++c2)
            raw[pl][c2] = gload16(pb, off[pl][c2]);
    }

    float acc[8] = {1.f, 1.f, 1.f, 1.f, 1.f, 1.f, 1.f, 1.f};

    // ---- consume plane-by-plane behind counted waits ----
#pragma unroll
    for (int pl = 0; pl < 3; ++pl) {
        if (pl == 0) VMWAIT(8);
        else if (pl == 1) VMWAIT(4);
        else VMWAIT(0);
        const __half2* f0 = (const __half2*)&raw[pl][0];
        const __half2* f1 = (const __half2*)&raw[pl][1];
        const __half2* f2 = (const __half2*)&raw[pl][2];
        const __half2* f3 = (const __half2*)&raw[pl][3];
        const float w00 = w[pl][0], w01 = w[pl][1];
        const float w10 = w[pl][2], w11 = w[pl][3];
#pragma unroll
        for (int i2 = 0; i2 < 4; ++i2) {
            const float2 a0 = __half22float2(f0[i2]);
            const float2 a1 = __half22float2(f1[i2]);
            const float2 a2 = __half22float2(f2[i2]);
            const float2 a3 = __half22float2(f3[i2]);
            acc[2 * i2 + 0] *= a0.x * w00 + a1.x * w01 + a2.x * w10 + a3.x * w11;
            acc[2 * i2 + 1] *= a0.y * w00 + a1.y * w01 + a2.y * w10 + a3.y * w11;
        }
    }

    float* o = out + (size_t)rec.w * C + h * 8;
    const v4f o0 = { acc[0], acc[1], acc[2], acc[3] };
    const v4f o1 = { acc[4], acc[5], acc[6], acc[7] };
    __builtin_nontemporal_store(o0, (v4f*)(o + 0));
    __builtin_nontemporal_store(o1, (v4f*)(o + 4));
}

// ============================ fallback paths ================================
__global__ __launch_bounds__(256) void transpose_chw_hwc(
    const float* __restrict__ p0, const float* __restrict__ p1,
    const float* __restrict__ p2, float* __restrict__ dst)
{
    __shared__ float lds[64 * 17];
    const int y  = blockIdx.x;
    const int x0 = blockIdx.y * 64;
    const int pl = blockIdx.z;
    const float* src = (pl == 0) ? p0 : ((pl == 1) ? p1 : p2);
    const int tid = threadIdx.x;
    const int xl  = tid & 63;
    const int c0  = tid >> 6;
#pragma unroll
    for (int i = 0; i < 4; ++i) {
        const int c = c0 * 4 + i;
        lds[xl * 17 + c] = src[c * HW + y * R + x0 + xl];
    }
    __syncthreads();
    float* dbase = dst + ((size_t)pl * HW + (size_t)(y * R + x0)) * C;
#pragma unroll
    for (int i = 0; i < 4; ++i) {
        const int j = tid + i * 256;
        dbase[j] = lds[(j >> 4) * 17 + (j & 15)];
    }
}

__global__ __launch_bounds__(256) void sample_hwc(
    const float* __restrict__ x, const float* __restrict__ t,
    float* __restrict__ out, int B)
{
    const int tid = blockIdx.x * 256 + threadIdx.x;
    const int p   = tid >> 2;
    const int cg  = tid & 3;
    if (p >= B) return;

    const float xv0 = x[(size_t)p * 3 + 0];
    const float xv1 = x[(size_t)p * 3 + 1];
    const float xv2 = x[(size_t)p * 3 + 2];
    const float gxs[3] = { xv0, xv0, xv1 };
    const float gys[3] = { xv1, xv2, xv2 };
    float4 acc = make_float4(1.f, 1.f, 1.f, 1.f);

#pragma unroll
    for (int pl = 0; pl < 3; ++pl) {
        const float gx = gxs[pl], gy = gys[pl];
        const float px = (gx + 1.0f) * 0.5f * (float)(R - 1);
        const float py = (gy + 1.0f) * 0.5f * (float)(R - 1);
        const float x0f = floorf(px), y0f = floorf(py);
        const float wx = px - x0f,   wy = py - y0f;
        int x0 = (int)x0f; x0 = min(max(x0, 0), R - 1);
        int y0 = (int)y0f; y0 = min(max(y0, 0), R - 1);
        const int x1 = min(x0 + 1, R - 1);
        const int y1 = min(y0 + 1, R - 1);

        const float* pb = t + (size_t)pl * (size_t)(HW * C) + cg * 4;
        const float4 p00 = *(const float4*)(pb + (size_t)(y0 * R + x0) * C);
        const float4 p01 = *(const float4*)(pb + (size_t)(y0 * R + x1) * C);
        const float4 p10 = *(const float4*)(pb + (size_t)(y1 * R + x0) * C);
        const float4 p11 = *(const float4*)(pb + (size_t)(y1 * R + x1) * C);

        const float w00 = (1.f - wx) * (1.f - wy);
        const float w01 = wx * (1.f - wy);
        const float w10 = (1.f - wx) * wy;
        const float w11 = wx * wy;

        float4 fv;
        fv.x = p00.x * w00 + p01.x * w01 + p10.x * w10 + p11.x * w11;
        fv.y = p00.y * w00 + p01.y * w01 + p10.y * w10 + p11.y * w11;
        fv.z = p00.z * w00 + p01.z * w01 + p10.z * w10 + p11.z * w11;
        fv.w = p00.w * w00 + p01.w * w01 + p10.w * w10 + p11.w * w11;

        acc.x *= fv.x; acc.y *= fv.y; acc.z *= fv.z; acc.w *= fv.w;
    }

    *(float4*)(out + (size_t)p * C + cg * 4) = acc;
}

__global__ __launch_bounds__(256) void sample_chw(
    const float* __restrict__ x,
    const float* __restrict__ p0, const float* __restrict__ p1,
    const float* __restrict__ p2, float* __restrict__ out, int B)
{
    const int tid = blockIdx.x * 256 + threadIdx.x;
    const int p   = tid >> 2;
    const int cg  = tid & 3;
    if (p >= B) return;
    const float xv0 = x[(size_t)p * 3 + 0];
    const float xv1 = x[(size_t)p * 3 + 1];
    const float xv2 = x[(size_t)p * 3 + 2];
    const float gxs[3] = { xv0, xv0, xv1 };
    const float gys[3] = { xv1, xv2, xv2 };
    const float* planes[3] = { p0, p1, p2 };
    float acc[4] = {1.f, 1.f, 1.f, 1.f};
#pragma unroll
    for (int pl = 0; pl < 3; ++pl) {
        const float gx = gxs[pl], gy = gys[pl];
        const float px = (gx + 1.0f) * 0.5f * (float)(R - 1);
        const float py = (gy + 1.0f) * 0.5f * (float)(R - 1);
        const float x0f = floorf(px), y0f = floorf(py);
        const float wx = px - x0f,   wy = py - y0f;
        int x0 = (int)x0f; x0 = min(max(x0, 0), R - 1);
        int y0 = (int)y0f; y0 = min(max(y0, 0), R - 1);
        const int x1 = min(x0 + 1, R - 1);
        const int y1 = min(y0 + 1, R - 1);
        const float w00 = (1.f - wx) * (1.f - wy);
        const float w01 = wx * (1.f - wy);
        const float w10 = (1.f - wx) * wy;
        const float w11 = wx * wy;
        const float* pb = planes[pl];
#pragma unroll
        for (int k = 0; k < 4; ++k) {
            const int c = cg * 4 + k;
            const float* b2 = pb + (size_t)c * HW;
            const float v00 = b2[y0 * R + x0];
            const float v01 = b2[y0 * R + x1];
            const float v10 = b2[y1 * R + x0];
            const float v11 = b2[y1 * R + x1];
            acc[k] *= v00 * w00 + v01 * w01 + v10 * w10 + v11 * w11;
        }
    }
    float* o = out + (size_t)p * C + cg * 4;
    o[0] = acc[0]; o[1] = acc[1]; o[2] = acc[2]; o[3] = acc[3];
}

// ===========================================================================
extern "C" void kernel_launch(void* const* d_in, const int* in_sizes, int n_in,
                              void* d_out, int out_size, void* d_ws, size_t ws_size,
                              hipStream_t stream) {
    const float* x  = (const float*)d_in[0];
    const float* p0 = (const float*)d_in[1];
    const float* p1 = (const float*)d_in[2];
    const float* p2 = (const float*)d_in[3];
    float* out = (float*)d_out;
    const int B = in_sizes[0] / 3;

    const size_t t_bytes    = (size_t)3 * HW * C * sizeof(__half);     // 24 MiB
    const size_t recs_bytes = (size_t)B * 16;                          // 32 MB
    const size_t cnt_bytes  = (size_t)NCNT * 4;                        // 16 KiB
    const size_t bs_bytes   = (size_t)(NB9 + 1) * 4;

    const size_t off_t      = 0;
    const size_t off_recs   = (t_bytes + 255) & ~(size_t)255;
    const size_t off_counts = (off_recs + recs_bytes + 255) & ~(size_t)255;
    const size_t off_cursor = (off_counts + cnt_bytes + 255) & ~(size_t)255;
    const size_t off_bs     = (off_cursor + cnt_bytes + 255) & ~(size_t)255;
    const size_t need_full  = off_bs + bs_bytes;

    const size_t need_fp32  = (size_t)3 * HW * C * sizeof(float);      // 48 MiB

    if (d_ws != nullptr && ws_size >= need_full) {
        __half*       t      = (__half*)((char*)d_ws + off_t);
        int4*         recs   = (int4*)((char*)d_ws + off_recs);
        unsigned int* counts = (unsigned int*)((char*)d_ws + off_counts);
        unsigned int* cursor = (unsigned int*)((char*)d_ws + off_cursor);
        unsigned int* bstart = (unsigned int*)((char*)d_ws + off_bs);

        dim3 tg(R, R / 64, 3);
        transpose_chw_hwc_h<<<tg, 256, 0, stream>>>(p0, p1, p2, t);

        hipMemsetAsync(counts, 0, cnt_bytes, stream);
        const int nblkP = (B + CHUNK - 1) / CHUNK;
        hist_pts<<<nblkP, 256, 0, stream>>>(x, counts, B);
        scan_counts<<<1, 1024, 0, stream>>>(counts, cursor, bstart);
        scatter_pts<<<nblkP, 256, 0, stream>>>(x, cursor, recs, B);
        refine_pts<<<NB9, 512, 0, stream>>>(bstart, recs);

        const int nthr2 = 2 * B;                   // 2 lanes/pt, 1 pt/thread
        const int nblk2 = (nthr2 + 255) / 256;
        const int q = nblk2 / 8, r = nblk2 % 8;
        sample_sorted<<<nblk2, 256, 0, stream>>>(recs, t, out, B, q, r);
    } else if (d_ws != nullptr && ws_size >= need_fp32) {
        float* tf = (float*)d_ws;
        dim3 tg(R, R / 64, 3);
        transpose_chw_hwc<<<tg, 256, 0, stream>>>(p0, p1, p2, tf);
        const int nthr = B * 4;
        const int nblk = (nthr + 255) / 256;
        sample_hwc<<<nblk, 256, 0, stream>>>(x, tf, out, B);
    } else {
        const int nthr = B * 4;
        const int nblk = (nthr + 255) / 256;
        sample_chw<<<nblk, 256, 0, stream>>>(x, p0, p1, p2, out, B);
    }
}

// Round 16
// 133.714 us; speedup vs baseline: 1.0946x; 1.0255x over previous
//
#include <hip/hip_runtime.h>
#include <hip/hip_fp16.h>
#include <cstdint>
#include <cstddef>

constexpr int R  = 512;
constexpr int C  = 16;
constexpr int HW = R * R;

constexpr int NB9   = 512;    // coarse bins: 3 bits/axis (64px cells)
constexpr int NPART = 8;      // XCD partitions for coarse counters
constexpr int NCNT  = NB9 * NPART;
constexpr int CHUNK = 4096;   // pts/block in hist/scatter
constexpr int KMAX  = 16;     // refine: recs per thread (cap 8192 per coarse bin)

typedef float v4f __attribute__((ext_vector_type(4)));
typedef int   v4i __attribute__((ext_vector_type(4)));

// ---- unified, bit-exact coordinate helpers ----------
__device__ __forceinline__ float tcoord(float g) {
    return __fmul_rn(__fadd_rn(g, 1.0f), 255.5f);   // bit-exact == ((g+1)*0.5f)*511
}
__device__ __forceinline__ int cell512(float g) {
    const int i = (int)tcoord(g);
    return min(max(i, 0), R - 1);
}
__device__ __forceinline__ uint32_t mortonN(int a, int b, int c, int nb) {
    uint32_t k = 0;
#pragma unroll
    for (int i = 0; i < 5; ++i) {
        if (i < nb) {
            k |= ((uint32_t)((a >> i) & 1)) << (3 * i + 2);
            k |= ((uint32_t)((b >> i) & 1)) << (3 * i + 1);
            k |= ((uint32_t)((c >> i) & 1)) << (3 * i + 0);
        }
    }
    return k;
}
__device__ __forceinline__ uint32_t key9(float a, float b, float c) {
    return mortonN(cell512(a) >> 6, cell512(b) >> 6, cell512(c) >> 6, 3);
}

// ---- forced-MLP gather primitives (inline asm, SADDR + 32-bit voffset) ----
__device__ __forceinline__ v4i gload16(const void* base, uint32_t voff) {
    v4i r;
    asm volatile("global_load_dwordx4 %0, %1, %2"
                 : "=&v"(r) : "v"(voff), "s"(base));
    return r;
}
#define VMWAIT(N) do { \
    asm volatile("s_waitcnt vmcnt(" #N ")" ::: "memory"); \
    __builtin_amdgcn_sched_barrier(0); \
} while (0)

// ---------------------------------------------------------------------------
// Transpose (C,H,W) fp32 -> (H,W,C) fp16 (interleaved 32B texels).
// ---------------------------------------------------------------------------
__global__ __launch_bounds__(256) void transpose_chw_hwc_h(
    const float* __restrict__ p0, const float* __restrict__ p1,
    const float* __restrict__ p2, __half* __restrict__ dst)
{
    __shared__ float lds[64 * 17];
    const int y  = blockIdx.x;
    const int x0 = blockIdx.y * 64;
    const int pl = blockIdx.z;
    const float* src = (pl == 0) ? p0 : ((pl == 1) ? p1 : p2);
    const int tid = threadIdx.x;
    const int xl  = tid & 63;
    const int c0  = tid >> 6;
#pragma unroll
    for (int i = 0; i < 4; ++i) {
        const int c = c0 * 4 + i;
        lds[xl * 17 + c] = src[c * HW + y * R + x0 + xl];
    }
    __syncthreads();
    __half2* dbase = (__half2*)(dst + ((size_t)pl * HW + (size_t)(y * R + x0)) * C);
#pragma unroll
    for (int i = 0; i < 2; ++i) {
        const int j  = tid + i * 256;
        const int e0 = 2 * j;
        const float a = lds[(e0 >> 4) * 17 + (e0 & 15)];
        const float b = lds[(e0 >> 4) * 17 + ((e0 & 15) + 1)];
        dbase[j] = __floats2half2_rn(a, b);
    }
}

// ---------------------------------------------------------------------------
// Coarse histogram (9-bit) with LDS aggregation.
// ---------------------------------------------------------------------------
__global__ __launch_bounds__(256) void hist_pts(
    const float* __restrict__ x, unsigned int* __restrict__ counts, int B)
{
    __shared__ unsigned int h[NB9];
    const int tid = threadIdx.x;
    for (int i = tid; i < NB9; i += 256) h[i] = 0;
    __syncthreads();
    const int start = blockIdx.x * CHUNK;
#pragma unroll
    for (int j = 0; j < CHUNK / 256; ++j) {
        const int i = start + j * 256 + tid;
        if (i < B) {
            const float a = x[(size_t)i * 3 + 0];
            const float b = x[(size_t)i * 3 + 1];
            const float c = x[(size_t)i * 3 + 2];
            atomicAdd(&h[key9(a, b, c)], 1u);
        }
    }
    __syncthreads();
    unsigned int* cb = counts + (blockIdx.x & (NPART - 1)) * NB9;
    for (int i = tid; i < NB9; i += 256) {
        const unsigned int c = h[i];
        if (c) atomicAdd(&cb[i], c);
    }
}

// Scan 4096 coarse counters in LOGICAL (key,part) order (records bin-major);
// counters part-major in memory. Emits binStart[key] for refine.
__global__ __launch_bounds__(1024) void scan_counts(
    const unsigned int* __restrict__ counts, unsigned int* __restrict__ cursor,
    unsigned int* __restrict__ binStart)
{
    __shared__ unsigned int s[1024];
    const int t = threadIdx.x;
    unsigned int v[4];
    unsigned int sum = 0;
#pragma unroll
    for (int i = 0; i < 4; ++i) {
        const int L = t * 4 + i;            // logical = key*NPART + part
        const int key = L >> 3, part = L & 7;
        v[i] = counts[part * NB9 + key];
        sum += v[i];
    }
    unsigned int run = 0;
#pragma unroll
    for (int i = 0; i < 4; ++i) { const unsigned int tmp = v[i]; v[i] = run; run += tmp; }
    s[t] = sum;
    __syncthreads();
    unsigned int incl = sum;
    for (int off = 1; off < 1024; off <<= 1) {
        const unsigned int u = (t >= off) ? s[t - off] : 0u;
        __syncthreads();
        incl += u;
        s[t] = incl;
        __syncthreads();
    }
    const unsigned int excl = incl - sum;
#pragma unroll
    for (int i = 0; i < 4; ++i) {
        const int L = t * 4 + i;
        const int key = L >> 3, part = L & 7;
        cursor[part * NB9 + key] = excl + v[i];
        if (part == 0) binStart[key] = excl + v[i];
    }
    if (t == 1023) binStart[NB9] = incl;    // = B
}

// ---------------------------------------------------------------------------
// Coarse scatter: block-local counting sort (bin-sorted, run-coalesced writes).
// ---------------------------------------------------------------------------
__global__ __launch_bounds__(256) void scatter_pts(
    const float* __restrict__ x, unsigned int* __restrict__ cursor,
    int4* __restrict__ recs, int B)
{
    __shared__ unsigned int h[NB9];
    __shared__ unsigned int gbase[NB9];
    __shared__ unsigned int lpre[NB9];
    __shared__ unsigned int lcur[NB9];
    __shared__ int4 buf[CHUNK];
    __shared__ unsigned short binOf[CHUNK];

    const int tid   = threadIdx.x;
    const int start = blockIdx.x * CHUNK;
    const int V     = min(CHUNK, B - start);

    for (int i = tid; i < NB9; i += 256) h[i] = 0;
    __syncthreads();

    float pa[CHUNK / 256], pb_[CHUNK / 256], pc[CHUNK / 256];
    unsigned int pk[CHUNK / 256];
#pragma unroll
    for (int j = 0; j < CHUNK / 256; ++j) {
        const int i = start + j * 256 + tid;
        pk[j] = 0xFFFFFFFFu;
        if (i < B) {
            pa[j] = x[(size_t)i * 3 + 0];
            pb_[j] = x[(size_t)i * 3 + 1];
            pc[j] = x[(size_t)i * 3 + 2];
            pk[j] = key9(pa[j], pb_[j], pc[j]);
            atomicAdd(&h[pk[j]], 1u);
        }
    }
    __syncthreads();

    unsigned int* cb = cursor + (blockIdx.x & (NPART - 1)) * NB9;
    for (int b = tid; b < NB9; b += 256) {
        const unsigned int c = h[b];
        gbase[b] = c ? atomicAdd(&cb[b], c) : 0u;
    }
    if (tid < 64) {
        unsigned int loc[8];
        unsigned int tot = 0;
#pragma unroll
        for (int j = 0; j < 8; ++j) { loc[j] = h[tid * 8 + j]; tot += loc[j]; }
        unsigned int run = tot;
#pragma unroll
        for (int d = 1; d < 64; d <<= 1) {
            const unsigned int u = __shfl_up(run, (unsigned)d, 64);
            if (tid >= d) run += u;
        }
        unsigned int excl = run - tot;
#pragma unroll
        for (int j = 0; j < 8; ++j) { lpre[tid * 8 + j] = excl; excl += loc[j]; }
    }
    __syncthreads();
    for (int b = tid; b < NB9; b += 256) lcur[b] = lpre[b];
    __syncthreads();

#pragma unroll
    for (int j = 0; j < CHUNK / 256; ++j) {
        if (pk[j] != 0xFFFFFFFFu) {
            const int i = start + j * 256 + tid;
            const unsigned int rk = atomicAdd(&lcur[pk[j]], 1u);
            buf[rk] = make_int4(__float_as_int(pa[j]), __float_as_int(pb_[j]),
                                __float_as_int(pc[j]), i);
            binOf[rk] = (unsigned short)pk[j];
        }
    }
    __syncthreads();

    for (int idx = tid; idx < V; idx += 256) {
        const int4 rc = buf[idx];
        const int  k  = binOf[idx];
        const unsigned int dest = gbase[k] + ((unsigned int)idx - lpre[k]);
        const v4i rv = { rc.x, rc.y, rc.z, rc.w };
        __builtin_nontemporal_store(rv, (v4i*)&recs[dest]);
    }
}

// ---------------------------------------------------------------------------
// Refine: in-place permutation of each coarse bin's records by the 6 finer
// Morton bits -> overall 15-bit order (16px cells). Records held in
// registers across the barrier; one block per coarse bin. (18-bit variant
// measured neutral-to-worse in round 15 — 15-bit is the optimum.)
// ---------------------------------------------------------------------------
__global__ __launch_bounds__(512) void refine_pts(
    const unsigned int* __restrict__ binStart, int4* __restrict__ recs)
{
    __shared__ unsigned int h[64];
    __shared__ unsigned int pre[64];
    const int k = blockIdx.x;
    const unsigned int s0 = binStart[k];
    const unsigned int s1 = binStart[k + 1];
    const int tid = threadIdx.x;
    if (tid < 64) h[tid] = 0;
    __syncthreads();

    int4 rc[KMAX];
    unsigned int rs[KMAX];                  // (rank<<6)|sub
#pragma unroll
    for (int j = 0; j < KMAX; ++j) {
        const unsigned int idx = s0 + (unsigned)tid + (unsigned)j * 512u;
        rs[j] = 0xFFFFFFFFu;
        if (idx < s1) {
            rc[j] = recs[idx];
            const int c0 = cell512(__int_as_float(rc[j].x)) >> 4;
            const int c1 = cell512(__int_as_float(rc[j].y)) >> 4;
            const int c2 = cell512(__int_as_float(rc[j].z)) >> 4;
            const unsigned int sub = mortonN(c0, c1, c2, 5) & 63u;
            const unsigned int rank = atomicAdd(&h[sub], 1u);
            rs[j] = (rank << 6) | sub;
        }
    }
    __syncthreads();

    if (tid < 64) {
        const unsigned int v = h[tid];
        unsigned int run = v;
#pragma unroll
        for (int d = 1; d < 64; d <<= 1) {
            const unsigned int u = __shfl_up(run, (unsigned)d, 64);
            if (tid >= d) run += u;
        }
        pre[tid] = run - v;
    }
    __syncthreads();

#pragma unroll
    for (int j = 0; j < KMAX; ++j) {
        if (rs[j] != 0xFFFFFFFFu) {
            const unsigned int sub  = rs[j] & 63u;
            const unsigned int rank = rs[j] >> 6;
            recs[s0 + pre[sub] + rank] = rc[j];
        }
    }
}

// ---------------------------------------------------------------------------
// Sampler, forced-MLP, 1 point per thread (2 lanes/pt, 8 channels per lane):
// 12 inline-asm global_load_dwordx4 issued back-to-back, consumed per-plane
// behind counted s_waitcnt vmcnt(8/4/0) + sched_barrier (guide rule #18).
// At the L1/TA divergent-line rate (~1 line/cycle/CU) — best measured config.
// ---------------------------------------------------------------------------
__global__ __launch_bounds__(256) void sample_sorted(
    const int4* __restrict__ recs, const __half* __restrict__ t,
    float* __restrict__ out, int B, int q, int r)
{
    const uint32_t bid  = blockIdx.x;
    const uint32_t xcd  = bid & 7u;
    const uint32_t slot = bid >> 3;
    const uint32_t base = (xcd < (uint32_t)r) ? xcd * (q + 1)
                                              : (uint32_t)r * (q + 1) + (xcd - r) * q;
    const uint32_t lb   = base + slot;

    const int tid = (int)(lb * 256u + threadIdx.x);
    const int p   = tid >> 1;
    const int h   = tid & 1;
    if (p >= B) return;

    const v4i rec = __builtin_nontemporal_load((const v4i*)&recs[p]);
    const float xv0 = __int_as_float(rec.x);
    const float xv1 = __int_as_float(rec.y);
    const float xv2 = __int_as_float(rec.z);

    // ---- coordinate math: weights + 12 byte offsets (32-bit) ----
    float w[3][4];
    uint32_t off[3][4];
    const uint32_t hofs = (uint32_t)h * 16u;
#pragma unroll
    for (int pl = 0; pl < 3; ++pl) {
        const float gx = (pl == 2) ? xv1 : xv0;
        const float gy = (pl == 0) ? xv1 : xv2;
        const float px = (gx + 1.0f) * 0.5f * (float)(R - 1);
        const float py = (gy + 1.0f) * 0.5f * (float)(R - 1);
        const float x0f = floorf(px), y0f = floorf(py);
        const float wx = px - x0f,   wy = py - y0f;
        int x0 = (int)x0f; x0 = min(max(x0, 0), R - 1);
        int y0 = (int)y0f; y0 = min(max(y0, 0), R - 1);
        const int x1 = min(x0 + 1, R - 1);
        const int y1 = min(y0 + 1, R - 1);
        off[pl][0] = ((uint32_t)(y0 * R) + (uint32_t)x0) * 32u + hofs;
        off[pl][1] = ((uint32_t)(y0 * R) + (uint32_t)x1) * 32u + hofs;
        off[pl][2] = ((uint32_t)(y1 * R) + (uint32_t)x0) * 32u + hofs;
        off[pl][3] = ((uint32_t)(y1 * R) + (uint32_t)x1) * 32u + hofs;
        w[pl][0] = (1.f - wx) * (1.f - wy);
        w[pl][1] = wx * (1.f - wy);
        w[pl][2] = (1.f - wx) * wy;
        w[pl][3] = wx * wy;
    }

    // ---- issue ALL 12 loads (volatile asm: order pinned, cannot sink) ----
    v4i raw[3][4];
#pragma unroll
    for (int pl = 0; pl < 3; ++pl) {
        const void* pb = (const char*)t + (size_t)pl * ((size_t)HW * C * 2);
#pragma unroll
        for (int c2 = 0; c2 < 4; ++c2)
            raw[pl][c2] = gload16(pb, off[pl][c2]);
    }

    float acc[8] = {1.f, 1.f, 1.f, 1.f, 1.f, 1.f, 1.f, 1.f};

    // ---- consume plane-by-plane behind counted waits ----
#pragma unroll
    for (int pl = 0; pl < 3; ++pl) {
        if (pl == 0) VMWAIT(8);
        else if (pl == 1) VMWAIT(4);
        else VMWAIT(0);
        const __half2* f0 = (const __half2*)&raw[pl][0];
        const __half2* f1 = (const __half2*)&raw[pl][1];
        const __half2* f2 = (const __half2*)&raw[pl][2];
        const __half2* f3 = (const __half2*)&raw[pl][3];
        const float w00 = w[pl][0], w01 = w[pl][1];
        const float w10 = w[pl][2], w11 = w[pl][3];
#pragma unroll
        for (int i2 = 0; i2 < 4; ++i2) {
            const float2 a0 = __half22float2(f0[i2]);
            const float2 a1 = __half22float2(f1[i2]);
            const float2 a2 = __half22float2(f2[i2]);
            const float2 a3 = __half22float2(f3[i2]);
            acc[2 * i2 + 0] *= a0.x * w00 + a1.x * w01 + a2.x * w10 + a3.x * w11;
            acc[2 * i2 + 1] *= a0.y * w00 + a1.y * w01 + a2.y * w10 + a3.y * w11;
        }
    }

    float* o = out + (size_t)rec.w * C + h * 8;
    const v4f o0 = { acc[0], acc[1], acc[2], acc[3] };
    const v4f o1 = { acc[4], acc[5], acc[6], acc[7] };
    __builtin_nontemporal_store(o0, (v4f*)(o + 0));
    __builtin_nontemporal_store(o1, (v4f*)(o + 4));
}

// ============================ fallback paths ================================
__global__ __launch_bounds__(256) void transpose_chw_hwc(
    const float* __restrict__ p0, const float* __restrict__ p1,
    const float* __restrict__ p2, float* __restrict__ dst)
{
    __shared__ float lds[64 * 17];
    const int y  = blockIdx.x;
    const int x0 = blockIdx.y * 64;
    const int pl = blockIdx.z;
    const float* src = (pl == 0) ? p0 : ((pl == 1) ? p1 : p2);
    const int tid = threadIdx.x;
    const int xl  = tid & 63;
    const int c0  = tid >> 6;
#pragma unroll
    for (int i = 0; i < 4; ++i) {
        const int c = c0 * 4 + i;
        lds[xl * 17 + c] = src[c * HW + y * R + x0 + xl];
    }
    __syncthreads();
    float* dbase = dst + ((size_t)pl * HW + (size_t)(y * R + x0)) * C;
#pragma unroll
    for (int i = 0; i < 4; ++i) {
        const int j = tid + i * 256;
        dbase[j] = lds[(j >> 4) * 17 + (j & 15)];
    }
}

__global__ __launch_bounds__(256) void sample_hwc(
    const float* __restrict__ x, const float* __restrict__ t,
    float* __restrict__ out, int B)
{
    const int tid = blockIdx.x * 256 + threadIdx.x;
    const int p   = tid >> 2;
    const int cg  = tid & 3;
    if (p >= B) return;

    const float xv0 = x[(size_t)p * 3 + 0];
    const float xv1 = x[(size_t)p * 3 + 1];
    const float xv2 = x[(size_t)p * 3 + 2];
    const float gxs[3] = { xv0, xv0, xv1 };
    const float gys[3] = { xv1, xv2, xv2 };
    float4 acc = make_float4(1.f, 1.f, 1.f, 1.f);

#pragma unroll
    for (int pl = 0; pl < 3; ++pl) {
        const float gx = gxs[pl], gy = gys[pl];
        const float px = (gx + 1.0f) * 0.5f * (float)(R - 1);
        const float py = (gy + 1.0f) * 0.5f * (float)(R - 1);
        const float x0f = floorf(px), y0f = floorf(py);
        const float wx = px - x0f,   wy = py - y0f;
        int x0 = (int)x0f; x0 = min(max(x0, 0), R - 1);
        int y0 = (int)y0f; y0 = min(max(y0, 0), R - 1);
        const int x1 = min(x0 + 1, R - 1);
        const int y1 = min(y0 + 1, R - 1);

        const float* pb = t + (size_t)pl * (size_t)(HW * C) + cg * 4;
        const float4 p00 = *(const float4*)(pb + (size_t)(y0 * R + x0) * C);
        const float4 p01 = *(const float4*)(pb + (size_t)(y0 * R + x1) * C);
        const float4 p10 = *(const float4*)(pb + (size_t)(y1 * R + x0) * C);
        const float4 p11 = *(const float4*)(pb + (size_t)(y1 * R + x1) * C);

        const float w00 = (1.f - wx) * (1.f - wy);
        const float w01 = wx * (1.f - wy);
        const float w10 = (1.f - wx) * wy;
        const float w11 = wx * wy;

        float4 fv;
        fv.x = p00.x * w00 + p01.x * w01 + p10.x * w10 + p11.x * w11;
        fv.y = p00.y * w00 + p01.y * w01 + p10.y * w10 + p11.y * w11;
        fv.z = p00.z * w00 + p01.z * w01 + p10.z * w10 + p11.z * w11;
        fv.w = p00.w * w00 + p01.w * w01 + p10.w * w10 + p11.w * w11;

        acc.x *= fv.x; acc.y *= fv.y; acc.z *= fv.z; acc.w *= fv.w;
    }

    *(float4*)(out + (size_t)p * C + cg * 4) = acc;
}

__global__ __launch_bounds__(256) void sample_chw(
    const float* __restrict__ x,
    const float* __restrict__ p0, const float* __restrict__ p1,
    const float* __restrict__ p2, float* __restrict__ out, int B)
{
    const int tid = blockIdx.x * 256 + threadIdx.x;
    const int p   = tid >> 2;
    const int cg  = tid & 3;
    if (p >= B) return;
    const float xv0 = x[(size_t)p * 3 + 0];
    const float xv1 = x[(size_t)p * 3 + 1];
    const float xv2 = x[(size_t)p * 3 + 2];
    const float gxs[3] = { xv0, xv0, xv1 };
    const float gys[3] = { xv1, xv2, xv2 };
    const float* planes[3] = { p0, p1, p2 };
    float acc[4] = {1.f, 1.f, 1.f, 1.f};
#pragma unroll
    for (int pl = 0; pl < 3; ++pl) {
        const float gx = gxs[pl], gy = gys[pl];
        const float px = (gx + 1.0f) * 0.5f * (float)(R - 1);
        const float py = (gy + 1.0f) * 0.5f * (float)(R - 1);
        const float x0f = floorf(px), y0f = floorf(py);
        const float wx = px - x0f,   wy = py - y0f;
        int x0 = (int)x0f; x0 = min(max(x0, 0), R - 1);
        int y0 = (int)y0f; y0 = min(max(y0, 0), R - 1);
        const int x1 = min(x0 + 1, R - 1);
        const int y1 = min(y0 + 1, R - 1);
        const float w00 = (1.f - wx) * (1.f - wy);
        const float w01 = wx * (1.f - wy);
        const float w10 = (1.f - wx) * wy;
        const float w11 = wx * wy;
        const float* pb = planes[pl];
#pragma unroll
        for (int k = 0; k < 4; ++k) {
            const int c = cg * 4 + k;
            const float* b2 = pb + (size_t)c * HW;
            const float v00 = b2[y0 * R + x0];
            const float v01 = b2[y0 * R + x1];
            const float v10 = b2[y1 * R + x0];
            const float v11 = b2[y1 * R + x1];
            acc[k] *= v00 * w00 + v01 * w01 + v10 * w10 + v11 * w11;
        }
    }
    float* o = out + (size_t)p * C + cg * 4;
    o[0] = acc[0]; o[1] = acc[1]; o[2] = acc[2]; o[3] = acc[3];
}

// ===========================================================================
extern "C" void kernel_launch(void* const* d_in, const int* in_sizes, int n_in,
                              void* d_out, int out_size, void* d_ws, size_t ws_size,
                              hipStream_t stream) {
    const float* x  = (const float*)d_in[0];
    const float* p0 = (const float*)d_in[1];
    const float* p1 = (const float*)d_in[2];
    const float* p2 = (const float*)d_in[3];
    float* out = (float*)d_out;
    const int B = in_sizes[0] / 3;

    const size_t t_bytes    = (size_t)3 * HW * C * sizeof(__half);     // 24 MiB
    const size_t recs_bytes = (size_t)B * 16;                          // 32 MB
    const size_t cnt_bytes  = (size_t)NCNT * 4;                        // 16 KiB
    const size_t bs_bytes   = (size_t)(NB9 + 1) * 4;

    const size_t off_t      = 0;
    const size_t off_recs   = (t_bytes + 255) & ~(size_t)255;
    const size_t off_counts = (off_recs + recs_bytes + 255) & ~(size_t)255;
    const size_t off_cursor = (off_counts + cnt_bytes + 255) & ~(size_t)255;
    const size_t off_bs     = (off_cursor + cnt_bytes + 255) & ~(size_t)255;
    const size_t need_full  = off_bs + bs_bytes;

    const size_t need_fp32  = (size_t)3 * HW * C * sizeof(float);      // 48 MiB

    if (d_ws != nullptr && ws_size >= need_full) {
        __half*       t      = (__half*)((char*)d_ws + off_t);
        int4*         recs   = (int4*)((char*)d_ws + off_recs);
        unsigned int* counts = (unsigned int*)((char*)d_ws + off_counts);
        unsigned int* cursor = (unsigned int*)((char*)d_ws + off_cursor);
        unsigned int* bstart = (unsigned int*)((char*)d_ws + off_bs);

        dim3 tg(R, R / 64, 3);
        transpose_chw_hwc_h<<<tg, 256, 0, stream>>>(p0, p1, p2, t);

        hipMemsetAsync(counts, 0, cnt_bytes, stream);
        const int nblkP = (B + CHUNK - 1) / CHUNK;
        hist_pts<<<nblkP, 256, 0, stream>>>(x, counts, B);
        scan_counts<<<1, 1024, 0, stream>>>(counts, cursor, bstart);
        scatter_pts<<<nblkP, 256, 0, stream>>>(x, cursor, recs, B);
        refine_pts<<<NB9, 512, 0, stream>>>(bstart, recs);

        const int nthr2 = 2 * B;                   // 2 lanes/pt, 1 pt/thread
        const int nblk2 = (nthr2 + 255) / 256;
        const int q = nblk2 / 8, r = nblk2 % 8;
        sample_sorted<<<nblk2, 256, 0, stream>>>(recs, t, out, B, q, r);
    } else if (d_ws != nullptr && ws_size >= need_fp32) {
        float* tf = (float*)d_ws;
        dim3 tg(R, R / 64, 3);
        transpose_chw_hwc<<<tg, 256, 0, stream>>>(p0, p1, p2, tf);
        const int nthr = B * 4;
        const int nblk = (nthr + 255) / 256;
        sample_hwc<<<nblk, 256, 0, stream>>>(x, tf, out, B);
    } else {
        const int nthr = B * 4;
        const int nblk = (nthr + 255) / 256;
        sample_chw<<<nblk, 256, 0, stream>>>(x, p0, p1, p2, out, B);
    }
}